// Round 7
// baseline (179.152 us; speedup 1.0000x reference)
//
#include <hip/hip_runtime.h>
#include <hip/hip_bf16.h>

// Fused CausalSelfAttention: x @ Wa^T + ba -> split heads -> causal flash attn
// -> y @ Wp^T + bp.  B=4, T=2048, C=768, H=12, hs=64.  bf16 MFMA, fp32 accum.
//
// ws (shorts): xb[8192*768] wab[2304*768] wpb[768*768] qkvb[8192*2304] yb[8192*768]
//              vtb[48*64*2048]  (~80 MB)

typedef __attribute__((ext_vector_type(8))) short bf16x8;
typedef __attribute__((ext_vector_type(4))) short bf16x4;
typedef __attribute__((ext_vector_type(4))) float f32x4;
typedef __attribute__((ext_vector_type(16))) float f32x16;

#define MFMA16(a, b, c) __builtin_amdgcn_mfma_f32_16x16x32_bf16((a), (b), (c), 0, 0, 0)
#define MFMA32(a, b, c) __builtin_amdgcn_mfma_f32_32x32x16_bf16((a), (b), (c), 0, 0, 0)

__device__ __forceinline__ unsigned short f2bfbits(float f) {
  return __builtin_bit_cast(unsigned short, __float2bfloat16(f));
}
__device__ __forceinline__ float bf2f(short b) {
  return __uint_as_float(((unsigned)(unsigned short)b) << 16);
}
__device__ __forceinline__ float fast_exp2(float x) {
#if __has_builtin(__builtin_amdgcn_exp2f)
  return __builtin_amdgcn_exp2f(x);
#else
  return __expf(x * 0.6931471805599453f);
#endif
}
// truncation-pack two fp32 -> one u32 of 2 bf16 (RTZ; P is ratio-normalized so bias cancels)
__device__ __forceinline__ unsigned pk2bf(float lo, float hi) {
  return (__builtin_bit_cast(unsigned, hi) & 0xffff0000u) |
         (__builtin_bit_cast(unsigned, lo) >> 16);
}

__device__ __forceinline__ void gload_lds16(const void* g, void* l) {
  __builtin_amdgcn_global_load_lds((const __attribute__((address_space(1))) void*)g,
                                   (__attribute__((address_space(3))) void*)l, 16, 0, 0);
}

// ---------------- fp32 -> bf16 convert (x, w_attn, w_proj fused) ----------------
__global__ __launch_bounds__(256) void cvt3(const float* __restrict__ x,
                                            const float* __restrict__ wa,
                                            const float* __restrict__ wp,
                                            unsigned short* __restrict__ xb,
                                            unsigned short* __restrict__ wab,
                                            unsigned short* __restrict__ wpb) {
  int i = blockIdx.x * 256 + threadIdx.x;
  const float* in;
  unsigned short* out;
  int j;
  if (i < 1572864) { in = x; out = xb; j = i; }
  else if (i < 2015232) { in = wa; out = wab; j = i - 1572864; }
  else { in = wp; out = wpb; j = i - 2015232; }
  float4 f = ((const float4*)in)[j];
  bf16x4 o;
  o[0] = (short)f2bfbits(f.x); o[1] = (short)f2bfbits(f.y);
  o[2] = (short)f2bfbits(f.z); o[3] = (short)f2bfbits(f.w);
  ((bf16x4*)out)[j] = o;
}

// ---------------- GEMM (m97 structure + chunk-XOR swizzle, rule #21) ----------------
template <typename OutT>
__global__ __launch_bounds__(256) void gemm_bt(const unsigned short* __restrict__ A,
                                               const unsigned short* __restrict__ Bt,
                                               const float* __restrict__ bias,
                                               OutT* __restrict__ C, int M, int N, int K) {
  __shared__ unsigned short As[128 * 64];
  __shared__ unsigned short Bs[128 * 64];
  const int tid = threadIdx.x;
  const int w = tid >> 6, l = tid & 63;
  const int g = l >> 4, li = l & 15;
  const int wm = w >> 1, wn = w & 1;
  const int m0 = blockIdx.y * 128, n0 = blockIdx.x * 128;

  const int scw = (l & 7) ^ ((l >> 3) & 7);
  const int swr = li & 7;

  f32x4 acc[4][4] = {};

  for (int kt = 0; kt < K; kt += 64) {
#pragma unroll
    for (int n = 0; n < 4; ++n) {
      int R = w * 32 + n * 8 + (l >> 3);
      gload_lds16(A + (long)(m0 + R) * K + kt + scw * 8, &As[(w * 32 + n * 8) * 64]);
      gload_lds16(Bt + (long)(n0 + R) * K + kt + scw * 8, &Bs[(w * 32 + n * 8) * 64]);
    }
    __syncthreads();
#pragma unroll
    for (int kk = 0; kk < 2; ++kk) {
      bf16x8 a[4], b[4];
#pragma unroll
      for (int m = 0; m < 4; ++m)
        a[m] = *(const bf16x8*)&As[(wm * 64 + m * 16 + li) * 64 + ((kk * 4 + g) ^ swr) * 8];
#pragma unroll
      for (int n = 0; n < 4; ++n)
        b[n] = *(const bf16x8*)&Bs[(wn * 64 + n * 16 + li) * 64 + ((kk * 4 + g) ^ swr) * 8];
#pragma unroll
      for (int m = 0; m < 4; ++m)
#pragma unroll
        for (int n = 0; n < 4; ++n) acc[m][n] = MFMA16(a[m], b[n], acc[m][n]);
    }
    __syncthreads();
  }

#pragma unroll
  for (int m = 0; m < 4; ++m) {
    int row = m0 + wm * 64 + m * 16 + 4 * g;
#pragma unroll
    for (int n = 0; n < 4; ++n) {
      int col = n0 + wn * 64 + n * 16 + li;
      float bi = bias[col];
#pragma unroll
      for (int r = 0; r < 4; ++r) {
        float v = acc[m][n][r] + bi;
        if constexpr (sizeof(OutT) == 2)
          C[(long)(row + r) * N + col] = (OutT)f2bfbits(v);
        else
          C[(long)(row + r) * N + col] = v;
      }
    }
  }
}

// ---------------- V transpose: qkv V-part -> Vt[bh][d][t] ----------------
__global__ __launch_bounds__(64) void transpose_v(const unsigned short* __restrict__ qkv,
                                                  unsigned short* __restrict__ vt) {
  const int kt = blockIdx.x & 31, bh = blockIdx.x >> 5;
  const int b = bh / 12, h = bh - b * 12;
  const int l = threadIdx.x;
  const int ct = l & 7, cd = l >> 3;

  bf16x8 tin[8], tout[8];
#pragma unroll
  for (int i = 0; i < 8; ++i)
    tin[i] = *(const bf16x8*)(qkv + (long)(b * 2048 + kt * 64 + ct * 8 + i) * 2304 +
                              1536 + h * 64 + cd * 8);
#pragma unroll
  for (int j = 0; j < 8; ++j) {
#pragma unroll
    for (int i = 0; i < 8; ++i) tout[j][i] = tin[i][j];
    *(bf16x8*)(vt + (long)(bh * 64 + cd * 8 + j) * 2048 + kt * 64 + ct * 8) = tout[j];
  }
}

// ---------------- attention helpers ----------------
__device__ __forceinline__ bf16x8 scale_bf8(bf16x8 v, float c) {
  bf16x8 o;
#pragma unroll
  for (int j = 0; j < 8; ++j) o[j] = (short)f2bfbits(bf2f(v[j]) * c);
  return o;
}

// softmax of one 64(k)x32(q) S^T state (log2 domain), fully in-register.
// s0/s1 = C/D of mfma(K,Q) for kn=0/1: lane q=lane&31, k=kn*32+crow(r,hi),
// crow(r,hi)=(r&3)+8*(r>>2)+4*hi [m74/m101-verified C/D layout].
// Produces pa[4] = PV A-operand fragments (k=16*ks+8*hi+j) via shfl_xor(32) exchange.
__device__ __forceinline__ void softmax_pack32(f32x16& s0, f32x16& s1, bool diag, int hi,
                                               int qloc, float& m, float& lsum, f32x16* o,
                                               bf16x8* pa) {
  if (diag) {
#pragma unroll
    for (int r = 0; r < 16; ++r) {
      int cr = (r & 3) + 8 * (r >> 2) + 4 * hi;
      if (cr > qloc) s0[r] = -1e30f;
      if (32 + cr > qloc) s1[r] = -1e30f;
    }
  }
  float pm = fmaxf(s0[0], s1[0]);
#pragma unroll
  for (int r = 1; r < 16; ++r) pm = fmaxf(pm, fmaxf(s0[r], s1[r]));
  pm = fmaxf(pm, __shfl_xor(pm, 32));

  if (!__all(pm - m <= 10.0f)) {  // defer-max (T13): rescale only on real growth
    float mn = fmaxf(m, pm);
    float alpha = fast_exp2(m - mn);
    m = mn;
    lsum *= alpha;
    float alo[16];
#pragma unroll
    for (int r = 0; r < 16; ++r) alo[r] = __shfl(alpha, (r & 3) + 8 * (r >> 2) + 4 * hi);
#pragma unroll
    for (int dn = 0; dn < 2; ++dn)
#pragma unroll
      for (int r = 0; r < 16; ++r) o[dn][r] *= alo[r];
  }

  // exp + in-lane sum + pack words C[kn][m*2+c] (m = r>>2)
  float ps = 0.f;
  unsigned C0[8], C1[8];
#pragma unroll
  for (int mm = 0; mm < 4; ++mm) {
    float e0 = fast_exp2(s0[4 * mm + 0] - m), e1 = fast_exp2(s0[4 * mm + 1] - m);
    float e2 = fast_exp2(s0[4 * mm + 2] - m), e3 = fast_exp2(s0[4 * mm + 3] - m);
    ps += (e0 + e1) + (e2 + e3);
    C0[2 * mm] = pk2bf(e0, e1);
    C0[2 * mm + 1] = pk2bf(e2, e3);
    float f0 = fast_exp2(s1[4 * mm + 0] - m), f1 = fast_exp2(s1[4 * mm + 1] - m);
    float f2 = fast_exp2(s1[4 * mm + 2] - m), f3 = fast_exp2(s1[4 * mm + 3] - m);
    ps += (f0 + f1) + (f2 + f3);
    C1[2 * mm] = pk2bf(f0, f1);
    C1[2 * mm + 1] = pk2bf(f2, f3);
  }
  ps += __shfl_xor(ps, 32);
  lsum += ps;

  // pa[kn*2+k2]: hi=0 lane needs m=2*k2 words (own + partner); hi=1 needs m=2*k2+1
#pragma unroll
  for (int kn = 0; kn < 2; ++kn) {
#pragma unroll
    for (int k2 = 0; k2 < 2; ++k2) {
      unsigned a0 = kn ? C1[4 * k2 + 0] : C0[4 * k2 + 0];
      unsigned a1 = kn ? C1[4 * k2 + 1] : C0[4 * k2 + 1];
      unsigned b0 = kn ? C1[4 * k2 + 2] : C0[4 * k2 + 2];
      unsigned b1 = kn ? C1[4 * k2 + 3] : C0[4 * k2 + 3];
      unsigned sa0 = (unsigned)__shfl_xor((int)a0, 32);
      unsigned sa1 = (unsigned)__shfl_xor((int)a1, 32);
      unsigned sb0 = (unsigned)__shfl_xor((int)b0, 32);
      unsigned sb1 = (unsigned)__shfl_xor((int)b1, 32);
      uint4 uu;
      uu.x = hi ? sb0 : a0;   // j=0,1
      uu.y = hi ? sb1 : a1;   // j=2,3
      uu.z = hi ? b0 : sa0;   // j=4,5
      uu.w = hi ? b1 : sa1;   // j=6,7
      pa[kn * 2 + k2] = __builtin_bit_cast(bf16x8, uu);
    }
  }
}

// one K/V tile vs one (DUAL=0) or two (DUAL=1) 32-q states; shared K/V LDS reads
template <bool DUAL>
__device__ __forceinline__ void attn_tile32(const unsigned short* Ks, const unsigned short* Vs,
                                            const bf16x8* bqh, const bf16x8* bql,
                                            bool diagh, bool diagl, int hi, int q31, int qloc,
                                            float& mh, float& lh, f32x16* oh,
                                            float& ml, float& ll, f32x16* ol) {
  const int swz = q31 & 7;
  f32x16 sh0 = {}, sh1 = {}, sl0 = {}, sl1 = {};
  __builtin_amdgcn_s_setprio(1);
#pragma unroll
  for (int dk = 0; dk < 4; ++dk) {
    bf16x8 ak0 = *(const bf16x8*)&Ks[q31 * 64 + ((2 * dk + hi) ^ swz) * 8];
    bf16x8 ak1 = *(const bf16x8*)&Ks[(32 + q31) * 64 + ((2 * dk + hi) ^ swz) * 8];
    sh0 = MFMA32(ak0, bqh[dk], sh0);
    sh1 = MFMA32(ak1, bqh[dk], sh1);
    if constexpr (DUAL) {
      sl0 = MFMA32(ak0, bql[dk], sl0);
      sl1 = MFMA32(ak1, bql[dk], sl1);
    }
  }
  __builtin_amdgcn_s_setprio(0);

  bf16x8 paH[4], paL[4];
  softmax_pack32(sh0, sh1, diagh, hi, qloc, mh, lh, oh, paH);
  if constexpr (DUAL) softmax_pack32(sl0, sl1, diagl, hi, qloc, ml, ll, ol, paL);

  __builtin_amdgcn_s_setprio(1);
#pragma unroll
  for (int ks = 0; ks < 4; ++ks) {
#pragma unroll
    for (int dn = 0; dn < 2; ++dn) {
      bf16x8 vb = *(const bf16x8*)&Vs[(dn * 32 + q31) * 64 + ((2 * ks + hi) ^ swz) * 8];
      oh[dn] = MFMA32(paH[ks], vb, oh[dn]);
      if constexpr (DUAL) ol[dn] = MFMA32(paL[ks], vb, ol[dn]);
    }
  }
  __builtin_amdgcn_s_setprio(0);
}

// ---------------- causal flash attention (32x32 MFMA, in-register softmax) ----------------
// 768 blocks x 128 threads (2 waves x 32 q-rows); paired q-tiles (p, 31-p); K/V dbuf LDS.
__global__ __launch_bounds__(128, 2) void attn_fwd(const unsigned short* __restrict__ qkv,
                                                   const unsigned short* __restrict__ vt,
                                                   unsigned short* __restrict__ y) {
  const int orig = (blockIdx.x & 7) * 96 + (blockIdx.x >> 3);  // XCD swizzle (768%8==0)
  const int bh = orig >> 4, p = orig & 15;
  const int b = bh / 12, h = bh - b * 12;
  const int qlo = p, qhi = 31 - p;
  const int tid = threadIdx.x;
  const int w = tid >> 6, l = tid & 63;
  const int q31 = l & 31, hi = l >> 5;
  const int qloc = w * 32 + q31;  // q within the 64-row tile

  __shared__ unsigned short Ks[2][64 * 64];
  __shared__ unsigned short Vs[2][64 * 64];

  const unsigned short* base = qkv + (long)b * 2048 * 2304;

  // Q fragments (B-operand: col=lane&31=q, k(d)=16*dk+8*hi+j), pre-scaled to exp2 domain
  const float QS = 0.18033688011112042f;
  bf16x8 bqhi[4], bqlo[4];
  {
    const unsigned short* qr = base + (long)(qhi * 64 + qloc) * 2304 + h * 64 + 8 * hi;
#pragma unroll
    for (int dk = 0; dk < 4; ++dk) bqhi[dk] = scale_bf8(*(const bf16x8*)(qr + dk * 16), QS);
    qr = base + (long)(qlo * 64 + qloc) * 2304 + h * 64 + 8 * hi;
#pragma unroll
    for (int dk = 0; dk < 4; ++dk) bqlo[dk] = scale_bf8(*(const bf16x8*)(qr + dk * 16), QS);
  }

  float m_lo = -1e30f, l_lo = 0.f, m_hi = -1e30f, l_hi = 0.f;
  f32x16 o_lo[2] = {}, o_hi[2] = {};

  const int sR8 = l >> 3, sc = l & 7;

  int buf = 0;
  {
#pragma unroll
    for (int i = 0; i < 4; ++i) {
      int R = w * 32 + i * 8 + sR8;
      int c = sc ^ (R & 7);
      gload_lds16(base + (long)R * 2304 + 768 + h * 64 + c * 8, &Ks[0][(w * 32 + i * 8) * 64]);
      gload_lds16(vt + (long)(bh * 64 + R) * 2048 + c * 8, &Vs[0][(w * 32 + i * 8) * 64]);
    }
  }
  __syncthreads();

  for (int kt = 0; kt <= qhi; ++kt) {
    if (kt < qhi) {
#pragma unroll
      for (int i = 0; i < 4; ++i) {
        int R = w * 32 + i * 8 + sR8;
        int c = sc ^ (R & 7);
        gload_lds16(base + (long)((kt + 1) * 64 + R) * 2304 + 768 + h * 64 + c * 8,
                    &Ks[buf ^ 1][(w * 32 + i * 8) * 64]);
        gload_lds16(vt + (long)(bh * 64 + R) * 2048 + (kt + 1) * 64 + c * 8,
                    &Vs[buf ^ 1][(w * 32 + i * 8) * 64]);
      }
    }
    if (kt <= qlo)
      attn_tile32<true>(Ks[buf], Vs[buf], bqhi, bqlo, kt == qhi, kt == qlo, hi, q31, qloc,
                        m_hi, l_hi, o_hi, m_lo, l_lo, o_lo);
    else
      attn_tile32<false>(Ks[buf], Vs[buf], bqhi, bqlo, kt == qhi, false, hi, q31, qloc,
                         m_hi, l_hi, o_hi, m_lo, l_lo, o_lo);
    __syncthreads();  // drains vmcnt (prefetch) + lgkm; protects buf swap
    buf ^= 1;
  }

  // epilogue: inv(lsum) lives at q=lane&31; redistribute to crow(r,hi) domain once
#pragma unroll
  for (int t = 0; t < 2; ++t) {
    const f32x16* o = t ? o_hi : o_lo;
    float inv = 1.0f / (t ? l_hi : l_lo);
    int qt = t ? qhi : qlo;
#pragma unroll
    for (int r = 0; r < 16; ++r) {
      int cr = (r & 3) + 8 * (r >> 2) + 4 * hi;
      float iq = __shfl(inv, (r & 3) + 8 * (r >> 2) + 4 * hi);
      long row = (long)b * 2048 + qt * 64 + w * 32 + cr;
#pragma unroll
      for (int dn = 0; dn < 2; ++dn)
        y[row * 768 + h * 64 + dn * 32 + q31] = (unsigned short)f2bfbits(o[dn][r] * iq);
    }
  }
}

// ---------------- launch ----------------
extern "C" void kernel_launch(void* const* d_in, const int* in_sizes, int n_in,
                              void* d_out, int out_size, void* d_ws, size_t ws_size,
                              hipStream_t stream) {
  const float* x      = (const float*)d_in[0];
  const float* w_attn = (const float*)d_in[1];
  const float* b_attn = (const float*)d_in[2];
  const float* w_proj = (const float*)d_in[3];
  const float* b_proj = (const float*)d_in[4];
  float* out = (float*)d_out;

  unsigned short* xb   = (unsigned short*)d_ws;
  unsigned short* wab  = xb + 6291456;                  // 8192*768
  unsigned short* wpb  = wab + 1769472;                 // 2304*768
  unsigned short* qkvb = wpb + 589824;                  // 768*768
  unsigned short* yb   = qkvb + (long)8192 * 2304;
  unsigned short* vtb  = yb + 6291456;                  // 48*64*2048

  cvt3<<<8448, 256, 0, stream>>>(x, w_attn, w_proj, xb, wab, wpb);

  gemm_bt<unsigned short><<<dim3(18, 64), 256, 0, stream>>>(xb, wab, b_attn, qkvb, 8192, 2304, 768);
  transpose_v<<<1536, 64, 0, stream>>>(qkvb, vtb);
  attn_fwd<<<768, 128, 0, stream>>>(qkvb, vtb, yb);
  gemm_bt<float><<<dim3(6, 64), 256, 0, stream>>>(yb, wpb, b_proj, out, 8192, 768, 768);
}

// Round 8
// 154.219 us; speedup vs baseline: 1.1617x; 1.1617x over previous
//
#include <hip/hip_runtime.h>
#include <hip/hip_bf16.h>

// Fused CausalSelfAttention: x @ Wa^T + ba -> split heads -> causal flash attn
// -> y @ Wp^T + bp.  B=4, T=2048, C=768, H=12, hs=64.  bf16 MFMA, fp32 accum.
//
// ws (shorts): xb[8192*768] wab[2304*768] wpb[768*768] qkvb[8192*2304] yb[8192*768]
//              vtb[48*64*2048]  (~80 MB)

typedef __attribute__((ext_vector_type(8))) short bf16x8;
typedef __attribute__((ext_vector_type(4))) short bf16x4;
typedef __attribute__((ext_vector_type(4))) float f32x4;
typedef __attribute__((ext_vector_type(16))) float f32x16;

#define MFMA16(a, b, c) __builtin_amdgcn_mfma_f32_16x16x32_bf16((a), (b), (c), 0, 0, 0)
#define MFMA32(a, b, c) __builtin_amdgcn_mfma_f32_32x32x16_bf16((a), (b), (c), 0, 0, 0)

__device__ __forceinline__ unsigned short f2bfbits(float f) {
  return __builtin_bit_cast(unsigned short, __float2bfloat16(f));
}
__device__ __forceinline__ float bf2f(short b) {
  return __uint_as_float(((unsigned)(unsigned short)b) << 16);
}
__device__ __forceinline__ float fast_exp2(float x) {
#if __has_builtin(__builtin_amdgcn_exp2f)
  return __builtin_amdgcn_exp2f(x);
#else
  return __expf(x * 0.6931471805599453f);
#endif
}
// truncation-pack two fp32 -> one u32 of 2 bf16 (RTZ; P is ratio-normalized so bias cancels)
__device__ __forceinline__ unsigned pk2bf(float lo, float hi) {
  return (__builtin_bit_cast(unsigned, hi) & 0xffff0000u) |
         (__builtin_bit_cast(unsigned, lo) >> 16);
}

__device__ __forceinline__ void gload_lds16(const void* g, void* l) {
  __builtin_amdgcn_global_load_lds((const __attribute__((address_space(1))) void*)g,
                                   (__attribute__((address_space(3))) void*)l, 16, 0, 0);
}

// ---------------- fp32 -> bf16 convert (x, w_attn, w_proj fused) ----------------
__global__ __launch_bounds__(256) void cvt3(const float* __restrict__ x,
                                            const float* __restrict__ wa,
                                            const float* __restrict__ wp,
                                            unsigned short* __restrict__ xb,
                                            unsigned short* __restrict__ wab,
                                            unsigned short* __restrict__ wpb) {
  int i = blockIdx.x * 256 + threadIdx.x;
  const float* in;
  unsigned short* out;
  int j;
  if (i < 1572864) { in = x; out = xb; j = i; }
  else if (i < 2015232) { in = wa; out = wab; j = i - 1572864; }
  else { in = wp; out = wpb; j = i - 2015232; }
  float4 f = ((const float4*)in)[j];
  bf16x4 o;
  o[0] = (short)f2bfbits(f.x); o[1] = (short)f2bfbits(f.y);
  o[2] = (short)f2bfbits(f.z); o[3] = (short)f2bfbits(f.w);
  ((bf16x4*)out)[j] = o;
}

// ---------------- GEMM (m97 structure + chunk-XOR swizzle, rule #21) ----------------
template <typename OutT>
__global__ __launch_bounds__(256) void gemm_bt(const unsigned short* __restrict__ A,
                                               const unsigned short* __restrict__ Bt,
                                               const float* __restrict__ bias,
                                               OutT* __restrict__ C, int M, int N, int K) {
  __shared__ unsigned short As[128 * 64];
  __shared__ unsigned short Bs[128 * 64];
  const int tid = threadIdx.x;
  const int w = tid >> 6, l = tid & 63;
  const int g = l >> 4, li = l & 15;
  const int wm = w >> 1, wn = w & 1;
  const int m0 = blockIdx.y * 128, n0 = blockIdx.x * 128;

  const int scw = (l & 7) ^ ((l >> 3) & 7);
  const int swr = li & 7;

  f32x4 acc[4][4] = {};

  for (int kt = 0; kt < K; kt += 64) {
#pragma unroll
    for (int n = 0; n < 4; ++n) {
      int R = w * 32 + n * 8 + (l >> 3);
      gload_lds16(A + (long)(m0 + R) * K + kt + scw * 8, &As[(w * 32 + n * 8) * 64]);
      gload_lds16(Bt + (long)(n0 + R) * K + kt + scw * 8, &Bs[(w * 32 + n * 8) * 64]);
    }
    __syncthreads();
#pragma unroll
    for (int kk = 0; kk < 2; ++kk) {
      bf16x8 a[4], b[4];
#pragma unroll
      for (int m = 0; m < 4; ++m)
        a[m] = *(const bf16x8*)&As[(wm * 64 + m * 16 + li) * 64 + ((kk * 4 + g) ^ swr) * 8];
#pragma unroll
      for (int n = 0; n < 4; ++n)
        b[n] = *(const bf16x8*)&Bs[(wn * 64 + n * 16 + li) * 64 + ((kk * 4 + g) ^ swr) * 8];
#pragma unroll
      for (int m = 0; m < 4; ++m)
#pragma unroll
        for (int n = 0; n < 4; ++n) acc[m][n] = MFMA16(a[m], b[n], acc[m][n]);
    }
    __syncthreads();
  }

#pragma unroll
  for (int m = 0; m < 4; ++m) {
    int row = m0 + wm * 64 + m * 16 + 4 * g;
#pragma unroll
    for (int n = 0; n < 4; ++n) {
      int col = n0 + wn * 64 + n * 16 + li;
      float bi = bias[col];
#pragma unroll
      for (int r = 0; r < 4; ++r) {
        float v = acc[m][n][r] + bi;
        if constexpr (sizeof(OutT) == 2)
          C[(long)(row + r) * N + col] = (OutT)f2bfbits(v);
        else
          C[(long)(row + r) * N + col] = v;
      }
    }
  }
}

// ---------------- V transpose: qkv V-part -> Vt[bh][d][t] ----------------
__global__ __launch_bounds__(64) void transpose_v(const unsigned short* __restrict__ qkv,
                                                  unsigned short* __restrict__ vt) {
  const int kt = blockIdx.x & 31, bh = blockIdx.x >> 5;
  const int b = bh / 12, h = bh - b * 12;
  const int l = threadIdx.x;
  const int ct = l & 7, cd = l >> 3;

  bf16x8 tin[8], tout[8];
#pragma unroll
  for (int i = 0; i < 8; ++i)
    tin[i] = *(const bf16x8*)(qkv + (long)(b * 2048 + kt * 64 + ct * 8 + i) * 2304 +
                              1536 + h * 64 + cd * 8);
#pragma unroll
  for (int j = 0; j < 8; ++j) {
#pragma unroll
    for (int i = 0; i < 8; ++i) tout[j][i] = tin[i][j];
    *(bf16x8*)(vt + (long)(bh * 64 + cd * 8 + j) * 2048 + kt * 64 + ct * 8) = tout[j];
  }
}

// ---------------- attention helpers ----------------
__device__ __forceinline__ bf16x8 scale_bf8(bf16x8 v, float c) {
  bf16x8 o;
#pragma unroll
  for (int j = 0; j < 8; ++j) o[j] = (short)f2bfbits(bf2f(v[j]) * c);
  return o;
}

// softmax of one 64(k)x32(q) S^T state (log2 domain), fully in-register.
// s0/s1 = C/D of mfma(K,Q): lane q=lane&31, k=kn*32+crow(r,hi), crow=(r&3)+8*(r>>2)+4*hi.
// Produces pa[4] = PV A-operand fragments (row=q, k=16*ks+8*hi+j) via shfl_xor(32).
__device__ __forceinline__ void softmax_pack32(f32x16& s0, f32x16& s1, bool diag, int hi,
                                               int qloc, float& m, float& lsum, f32x16* o,
                                               bf16x8* pa) {
  if (diag) {
#pragma unroll
    for (int r = 0; r < 16; ++r) {
      int cr = (r & 3) + 8 * (r >> 2) + 4 * hi;
      if (cr > qloc) s0[r] = -1e30f;
      if (32 + cr > qloc) s1[r] = -1e30f;
    }
  }
  float pm = fmaxf(s0[0], s1[0]);
#pragma unroll
  for (int r = 1; r < 16; ++r) pm = fmaxf(pm, fmaxf(s0[r], s1[r]));
  pm = fmaxf(pm, __shfl_xor(pm, 32));

  if (!__all(pm - m <= 10.0f)) {  // defer-max (T13): rescale only on real growth
    float mn = fmaxf(m, pm);
    float alpha = fast_exp2(m - mn);
    m = mn;
    lsum *= alpha;
    float alo[16];
#pragma unroll
    for (int r = 0; r < 16; ++r) alo[r] = __shfl(alpha, (r & 3) + 8 * (r >> 2) + 4 * hi);
#pragma unroll
    for (int dn = 0; dn < 2; ++dn)
#pragma unroll
      for (int r = 0; r < 16; ++r) o[dn][r] *= alo[r];
  }

  // exp + in-lane sum + pack words C[kn][m*2+c]
  float ps = 0.f;
  unsigned C0[8], C1[8];
#pragma unroll
  for (int mm = 0; mm < 4; ++mm) {
    float e0 = fast_exp2(s0[4 * mm + 0] - m), e1 = fast_exp2(s0[4 * mm + 1] - m);
    float e2 = fast_exp2(s0[4 * mm + 2] - m), e3 = fast_exp2(s0[4 * mm + 3] - m);
    ps += (e0 + e1) + (e2 + e3);
    C0[2 * mm] = pk2bf(e0, e1);
    C0[2 * mm + 1] = pk2bf(e2, e3);
    float f0 = fast_exp2(s1[4 * mm + 0] - m), f1 = fast_exp2(s1[4 * mm + 1] - m);
    float f2 = fast_exp2(s1[4 * mm + 2] - m), f3 = fast_exp2(s1[4 * mm + 3] - m);
    ps += (f0 + f1) + (f2 + f3);
    C1[2 * mm] = pk2bf(f0, f1);
    C1[2 * mm + 1] = pk2bf(f2, f3);
  }
  ps += __shfl_xor(ps, 32);
  lsum += ps;

  // pa[kn*2+k2]: hi=0 lane needs m=2*k2 words (own + partner); hi=1 needs m=2*k2+1
#pragma unroll
  for (int kn = 0; kn < 2; ++kn) {
#pragma unroll
    for (int k2 = 0; k2 < 2; ++k2) {
      unsigned a0 = kn ? C1[4 * k2 + 0] : C0[4 * k2 + 0];
      unsigned a1 = kn ? C1[4 * k2 + 1] : C0[4 * k2 + 1];
      unsigned b0 = kn ? C1[4 * k2 + 2] : C0[4 * k2 + 2];
      unsigned b1 = kn ? C1[4 * k2 + 3] : C0[4 * k2 + 3];
      unsigned sa0 = (unsigned)__shfl_xor((int)a0, 32);
      unsigned sa1 = (unsigned)__shfl_xor((int)a1, 32);
      unsigned sb0 = (unsigned)__shfl_xor((int)b0, 32);
      unsigned sb1 = (unsigned)__shfl_xor((int)b1, 32);
      uint4 uu;
      uu.x = hi ? sb0 : a0;   // j=0,1
      uu.y = hi ? sb1 : a1;   // j=2,3
      uu.z = hi ? b0 : sa0;   // j=4,5
      uu.w = hi ? b1 : sa1;   // j=6,7
      pa[kn * 2 + k2] = __builtin_bit_cast(bf16x8, uu);
    }
  }
}

// one K/V tile vs one 32-q state (single wave)
__device__ __forceinline__ void attn_tile32(const unsigned short* Ks, const unsigned short* Vs,
                                            const bf16x8* bq, bool diag, int hi, int q31,
                                            int qloc, float& m, float& lsum, f32x16* o) {
  const int swz = q31 & 7;
  f32x16 s0 = {}, s1 = {};
  __builtin_amdgcn_s_setprio(1);
#pragma unroll
  for (int dk = 0; dk < 4; ++dk) {
    bf16x8 ak0 = *(const bf16x8*)&Ks[q31 * 64 + ((2 * dk + hi) ^ swz) * 8];
    bf16x8 ak1 = *(const bf16x8*)&Ks[(32 + q31) * 64 + ((2 * dk + hi) ^ swz) * 8];
    s0 = MFMA32(ak0, bq[dk], s0);
    s1 = MFMA32(ak1, bq[dk], s1);
  }
  __builtin_amdgcn_s_setprio(0);

  bf16x8 pa[4];
  softmax_pack32(s0, s1, diag, hi, qloc, m, lsum, o, pa);

  __builtin_amdgcn_s_setprio(1);
#pragma unroll
  for (int ks = 0; ks < 4; ++ks) {
#pragma unroll
    for (int dn = 0; dn < 2; ++dn) {
      bf16x8 vb = *(const bf16x8*)&Vs[(dn * 32 + q31) * 64 + ((2 * ks + hi) ^ swz) * 8];
      o[dn] = MFMA32(pa[ks], vb, o[dn]);
    }
  }
  __builtin_amdgcn_s_setprio(0);
}

// ---------------- causal flash attention (32x32 MFMA, in-reg softmax, 4 waves) ----------------
// 768 blocks x 256 threads. Waves 0,1 -> hi tile halves; waves 2,3 -> lo tile halves.
__global__ __launch_bounds__(256, 3) void attn_fwd(const unsigned short* __restrict__ qkv,
                                                   const unsigned short* __restrict__ vt,
                                                   unsigned short* __restrict__ y) {
  const int orig = (blockIdx.x & 7) * 96 + (blockIdx.x >> 3);  // XCD swizzle (768%8==0)
  const int bh = orig >> 4, p = orig & 15;
  const int b = bh / 12, h = bh - b * 12;
  const int qlo = p, qhi = 31 - p;
  const int tid = threadIdx.x;
  const int w = tid >> 6, l = tid & 63;
  const int q31 = l & 31, hi = l >> 5;
  const bool isHi = (w < 2);
  const int halfq = (w & 1) * 32;
  const int qt = isHi ? qhi : qlo;
  const int qloc = halfq + q31;   // q within the 64-row tile

  __shared__ unsigned short Ks[2][64 * 64];
  __shared__ unsigned short Vs[2][64 * 64];

  const unsigned short* base = qkv + (long)b * 2048 * 2304;

  // Q fragments (B-operand: col=lane&31=q, k(d)=16*dk+8*hi+j), pre-scaled to exp2 domain
  const float QS = 0.18033688011112042f;
  bf16x8 bq[4];
  {
    const unsigned short* qr = base + (long)(qt * 64 + qloc) * 2304 + h * 64 + 8 * hi;
#pragma unroll
    for (int dk = 0; dk < 4; ++dk) bq[dk] = scale_bf8(*(const bf16x8*)(qr + dk * 16), QS);
  }

  float m = -1e30f, lsum = 0.f;
  f32x16 o[2] = {};

  // staging: 256 threads cover 64 rows x 8 chunks for K and V (2 iters each)
  const int sR8 = l >> 3, sc = l & 7;

  int buf = 0;
  {
#pragma unroll
    for (int i = 0; i < 2; ++i) {
      int R = i * 32 + w * 8 + sR8;
      int c = sc ^ (R & 7);
      gload_lds16(base + (long)R * 2304 + 768 + h * 64 + c * 8, &Ks[0][(i * 32 + w * 8) * 64]);
      gload_lds16(vt + (long)(bh * 64 + R) * 2048 + c * 8, &Vs[0][(i * 32 + w * 8) * 64]);
    }
  }
  __syncthreads();

  for (int kt = 0; kt <= qhi; ++kt) {
    if (kt < qhi) {
#pragma unroll
      for (int i = 0; i < 2; ++i) {
        int R = i * 32 + w * 8 + sR8;
        int c = sc ^ (R & 7);
        gload_lds16(base + (long)((kt + 1) * 64 + R) * 2304 + 768 + h * 64 + c * 8,
                    &Ks[buf ^ 1][(i * 32 + w * 8) * 64]);
        gload_lds16(vt + (long)(bh * 64 + R) * 2048 + (kt + 1) * 64 + c * 8,
                    &Vs[buf ^ 1][(i * 32 + w * 8) * 64]);
      }
    }
    if (isHi || kt <= qlo)
      attn_tile32(Ks[buf], Vs[buf], bq, kt == qt, hi, q31, qloc, m, lsum, o);
    __syncthreads();  // drains vmcnt (prefetch) + lgkm; protects buf swap
    buf ^= 1;
  }

  // epilogue: inv(lsum) lives at q=lane&31; redistribute to crow(r,hi) domain once
  {
    float inv = 1.0f / lsum;
#pragma unroll
    for (int r = 0; r < 16; ++r) {
      int cr = (r & 3) + 8 * (r >> 2) + 4 * hi;
      float iq = __shfl(inv, cr);
      long row = (long)b * 2048 + qt * 64 + halfq + cr;
#pragma unroll
      for (int dn = 0; dn < 2; ++dn)
        y[row * 768 + h * 64 + dn * 32 + q31] = (unsigned short)f2bfbits(o[dn][r] * iq);
    }
  }
}

// ---------------- launch ----------------
extern "C" void kernel_launch(void* const* d_in, const int* in_sizes, int n_in,
                              void* d_out, int out_size, void* d_ws, size_t ws_size,
                              hipStream_t stream) {
  const float* x      = (const float*)d_in[0];
  const float* w_attn = (const float*)d_in[1];
  const float* b_attn = (const float*)d_in[2];
  const float* w_proj = (const float*)d_in[3];
  const float* b_proj = (const float*)d_in[4];
  float* out = (float*)d_out;

  unsigned short* xb   = (unsigned short*)d_ws;
  unsigned short* wab  = xb + 6291456;                  // 8192*768
  unsigned short* wpb  = wab + 1769472;                 // 2304*768
  unsigned short* qkvb = wpb + 589824;                  // 768*768
  unsigned short* yb   = qkvb + (long)8192 * 2304;
  unsigned short* vtb  = yb + 6291456;                  // 48*64*2048

  cvt3<<<8448, 256, 0, stream>>>(x, w_attn, w_proj, xb, wab, wpb);

  gemm_bt<unsigned short><<<dim3(18, 64), 256, 0, stream>>>(xb, wab, b_attn, qkvb, 8192, 2304, 768);
  transpose_v<<<1536, 64, 0, stream>>>(qkvb, vtb);
  attn_fwd<<<768, 256, 0, stream>>>(qkvb, vtb, yb);
  gemm_bt<float><<<dim3(6, 64), 256, 0, stream>>>(yb, wpb, b_proj, out, 8192, 768, 768);
}